// Round 7
// baseline (2328.527 us; speedup 1.0000x reference)
//
#include <hip/hip_runtime.h>
#include <cmath>

#define NNODES 100000
#define NEDGES 1600000
#define INC 512
#define HC 256
#define NLAYERS 8

typedef _Float16 half8 __attribute__((ext_vector_type(8)));
typedef _Float16 half4v __attribute__((ext_vector_type(4)));
typedef float floatx4 __attribute__((ext_vector_type(4)));

struct __attribute__((aligned(8))) EdgeP { int s; float w; };

// ---- edge dtype detection: int64 little-endian with values < 2^31 => odd 32-bit words all zero.
__global__ void k_detect(const unsigned int* __restrict__ eb, int* __restrict__ mode) {
  int lane = threadIdx.x;  // 64 threads
  unsigned v = eb[2 * lane + 1];
  unsigned long long nz = __ballot(v != 0u);
  if (lane == 0) *mode = (nz == 0ull) ? 1 : 0;
}

__device__ __forceinline__ int edge_at(const void* eb, int m, int i) {
  return m ? (int)((const long long*)eb)[i] : ((const int*)eb)[i];
}

// ---------------- CSR build (unchanged, green since R3) ----------------

__global__ __launch_bounds__(256) void k_zero2(int* __restrict__ a, int* __restrict__ b, int n) {
  int i = blockIdx.x * 256 + threadIdx.x;
  if (i < n) { a[i] = 0; b[i] = 0; }
}

__global__ __launch_bounds__(256) void k_count(const void* __restrict__ eb, const int* __restrict__ mode,
                                               int* __restrict__ counts) {
  int e = blockIdx.x * 256 + threadIdx.x;
  if (e >= NEDGES) return;
  int m = *mode;
  atomicAdd(&counts[edge_at(eb, m, NEDGES + e)], 1);
}

__global__ __launch_bounds__(256) void k_dinv(const int* __restrict__ counts, float* __restrict__ dinv) {
  int i = blockIdx.x * 256 + threadIdx.x;
  if (i < NNODES) dinv[i] = 1.0f / sqrtf((float)counts[i] + 1.0f);  // +1 self loop
}

__global__ __launch_bounds__(256) void k_scan1(const int* __restrict__ counts, int* __restrict__ rowptr,
                                               int* __restrict__ partials) {
  __shared__ int sm[256];
  int i = blockIdx.x * 256 + threadIdx.x;
  int v = (i < NNODES) ? counts[i] : 0;
  sm[threadIdx.x] = v;
  __syncthreads();
  for (int off = 1; off < 256; off <<= 1) {
    int u = (threadIdx.x >= off) ? sm[threadIdx.x - off] : 0;
    __syncthreads();
    sm[threadIdx.x] += u;
    __syncthreads();
  }
  if (i < NNODES) rowptr[i] = sm[threadIdx.x] - v;
  if (threadIdx.x == 255) partials[blockIdx.x] = sm[255];
}

__global__ __launch_bounds__(512) void k_scan2(int* __restrict__ partials, int* __restrict__ rowptr, int nb) {
  __shared__ int sm[512];
  int t = threadIdx.x;
  int v = (t < nb) ? partials[t] : 0;
  sm[t] = v;
  __syncthreads();
  for (int off = 1; off < 512; off <<= 1) {
    int u = (t >= off) ? sm[t - off] : 0;
    __syncthreads();
    sm[t] += u;
    __syncthreads();
  }
  if (t < nb) partials[t] = sm[t] - v;
  if (t == 0) rowptr[NNODES] = NEDGES;
}

__global__ __launch_bounds__(256) void k_scan3(int* __restrict__ rowptr, const int* __restrict__ partials) {
  int i = blockIdx.x * 256 + threadIdx.x;
  if (i < NNODES) rowptr[i] += partials[blockIdx.x];
}

__global__ __launch_bounds__(256) void k_fill(const void* __restrict__ eb, const int* __restrict__ mode,
                                              const int* __restrict__ rowptr,
                                              int* __restrict__ cursor, const float* __restrict__ dinv,
                                              EdgeP* __restrict__ ep) {
  int e = blockIdx.x * 256 + threadIdx.x;
  if (e >= NEDGES) return;
  int m = *mode;
  int r = edge_at(eb, m, e), c = edge_at(eb, m, NEDGES + e);
  int p = rowptr[c] + atomicAdd(&cursor[c], 1);
  EdgeP pr; pr.s = r; pr.w = dinv[r] * dinv[c];
  ep[p] = pr;
}

// ---------------- weight transposes to f16 ----------------
__global__ __launch_bounds__(256) void k_tr_wemb(const float* __restrict__ W, _Float16* __restrict__ WT) {
  int idx = blockIdx.x * 256 + threadIdx.x;        // 131072 = c*512 + k
  int k = idx & 511, c = idx >> 9;
  WT[idx] = (_Float16)W[k * 256 + c];
}
__global__ __launch_bounds__(256) void k_tr_wc(const float* __restrict__ W, _Float16* __restrict__ WT) {
  int idx = blockIdx.x * 256 + threadIdx.x;        // 524288 = l*65536 + n*256 + k
  int k = idx & 255, n = (idx >> 8) & 255, l = idx >> 16;
  WT[idx] = (_Float16)W[(l * 256 + k) * 256 + n];
}

// ---------------- embed (unchanged from green R6): h0 = relu(x @ Wemb + b) ----------------

template <int K, bool AF16, bool BIAS, bool ID, bool RELU, bool F16OUT>
__global__ __launch_bounds__(256) void k_dense(const void* A, const _Float16* __restrict__ WT,
                                               const float* __restrict__ bias,
                                               const void* mfid,
                                               float ob, float beta,
                                               _Float16* __restrict__ outh, _Float16* __restrict__ outh2,
                                               float* outf) {
  int t = threadIdx.x;
  int wave = t >> 6, lane = t & 63;
  int r = lane & 15, g = lane >> 4;
  int row0 = blockIdx.x * 64;
  int c0 = wave * 64;
  int ar[4];
#pragma unroll
  for (int rt = 0; rt < 4; ++rt) {
    int rr = row0 + rt * 16 + r;
    ar[rt] = (rr < NNODES) ? rr : (NNODES - 1);
  }

  auto loadA = [&](half8 (&a)[4], int ks) {
#pragma unroll
    for (int rt = 0; rt < 4; ++rt) {
      if constexpr (AF16) {
        a[rt] = *(const half8*)((const _Float16*)A + (size_t)ar[rt] * K + ks + g * 8);
      } else {
        const float* ap = (const float*)A + (size_t)ar[rt] * K + ks + g * 8;
        float4 p0 = *(const float4*)ap;
        float4 p1 = *(const float4*)(ap + 4);
        a[rt] = half8{ (_Float16)p0.x, (_Float16)p0.y, (_Float16)p0.z, (_Float16)p0.w,
                       (_Float16)p1.x, (_Float16)p1.y, (_Float16)p1.z, (_Float16)p1.w };
      }
    }
  };
  auto loadB = [&](half8 (&b)[4], int ks) {
#pragma unroll
    for (int ct = 0; ct < 4; ++ct)
      b[ct] = *(const half8*)(WT + (size_t)(c0 + ct * 16 + r) * K + ks + g * 8);
  };

  floatx4 acc[4][4] = {};
  half8 aP[4], bP[4], aQ[4], bQ[4];
  loadA(aP, 0); loadB(bP, 0);
#pragma unroll
  for (int ks = 0; ks < K; ks += 64) {
    loadA(aQ, ks + 32); loadB(bQ, ks + 32);
#pragma unroll
    for (int rt = 0; rt < 4; ++rt)
#pragma unroll
      for (int ct = 0; ct < 4; ++ct)
        acc[rt][ct] = __builtin_amdgcn_mfma_f32_16x16x32_f16(aP[rt], bP[ct], acc[rt][ct], 0, 0, 0);
    if (ks + 64 < K) { loadA(aP, ks + 64); loadB(bP, ks + 64); }
#pragma unroll
    for (int rt = 0; rt < 4; ++rt)
#pragma unroll
      for (int ct = 0; ct < 4; ++ct)
        acc[rt][ct] = __builtin_amdgcn_mfma_f32_16x16x32_f16(aQ[rt], bQ[ct], acc[rt][ct], 0, 0, 0);
  }

  auto idval = [&](size_t off) -> float {
    if constexpr (AF16) return (float)((const _Float16*)mfid)[off];
    else return ((const float*)mfid)[off];
  };

  if constexpr (!F16OUT) {
    __syncthreads();
#pragma unroll
    for (int rt = 0; rt < 4; ++rt) {
#pragma unroll
      for (int q = 0; q < 4; ++q) {
        int row = row0 + rt * 16 + g * 4 + q;
        if (row >= NNODES) continue;
#pragma unroll
        for (int ct = 0; ct < 4; ++ct) {
          int col = c0 + ct * 16 + r;
          size_t off = (size_t)row * HC + col;
          float v = acc[rt][ct][q];
          if constexpr (ID) v = ob * idval(off) + beta * v;
          if constexpr (BIAS) v += bias[col];
          if constexpr (RELU) v = fmaxf(v, 0.0f);
          outf[off] = v;
        }
      }
    }
  } else {
    __shared__ _Float16 Cl[64][264];   // +8 f16 pad
#pragma unroll
    for (int rt = 0; rt < 4; ++rt) {
#pragma unroll
      for (int q = 0; q < 4; ++q) {
        int lrow = rt * 16 + g * 4 + q;
        int row = row0 + lrow;
        int crow = (row < NNODES) ? row : (NNODES - 1);
#pragma unroll
        for (int ct = 0; ct < 4; ++ct) {
          int col = c0 + ct * 16 + r;
          float v = acc[rt][ct][q];
          if constexpr (ID) v = ob * idval((size_t)crow * HC + col) + beta * v;
          if constexpr (BIAS) v += bias[col];
          if constexpr (RELU) v = fmaxf(v, 0.0f);
          Cl[lrow][col] = (_Float16)v;
        }
      }
    }
    __syncthreads();
    int lrow = t >> 2, cc = (t & 3) * 64;
    int grow = row0 + lrow;
    if (grow < NNODES) {
      size_t base = (size_t)grow * HC + cc;
#pragma unroll
      for (int i = 0; i < 8; ++i) {
        half8 v = *(const half8*)&Cl[lrow][cc + i * 8];
        *(half8*)(outh + base + i * 8) = v;
        if (outh2) *(half8*)(outh2 + base + i * 8) = v;
      }
    }
  }
}

// ---------------- fused layer: hn = relu( ob*m + beta*(m @ W) ), m built in LDS ----------------
// m = 0.9*(D^-1/2 A_hat D^-1/2 h) + 0.1*h0, staged in padded LDS tile M[64][264] f16.
// Phase 1: 4 waves x 16 nodes each, gather (wave-uniform node, lane covers 4 ch).
// Phase 2: proven MFMA dense, A-frags ds_read from M (16B-aligned, ~2-way banks).
// Epilogue (mid): thread-own in-place overwrite of M (same thread reads+writes its
// (row,col) after a barrier drains all A-frag reads), then coalesced half8 store.
// LAST: f32 direct stores to outf (full 64B lines), no M writes.

template <bool LAST>
__global__ __launch_bounds__(256) void k_layer(const _Float16* __restrict__ h,
                                               const _Float16* __restrict__ h0,
                                               const int* __restrict__ rowptr,
                                               const EdgeP* __restrict__ ep,
                                               const float* __restrict__ dinv,
                                               const _Float16* __restrict__ WT,
                                               float ob, float beta,
                                               _Float16* __restrict__ hn, float* __restrict__ outf) {
  __shared__ _Float16 M[64][264];
  int t = threadIdx.x;
  int wave = t >> 6, lane = t & 63;
  int row0 = blockIdx.x * 64;
  int c = lane * 4;

  // ---- phase 1: spmm + residual into M
  for (int i = 0; i < 16; ++i) {
    int lrow = wave * 16 + i;
    int node = row0 + lrow;
    if (node < NNODES) {
      size_t base = (size_t)node * HC + c;
      float di = dinv[node];
      float wsw = di * di;
      half4v hv = *(const half4v*)(h + base);
      float a0 = wsw * (float)hv[0], a1 = wsw * (float)hv[1];
      float a2 = wsw * (float)hv[2], a3 = wsw * (float)hv[3];
      int e = rowptr[node], en = rowptr[node + 1];
      for (; e + 3 < en; e += 4) {
        EdgeP p0 = ep[e], p1 = ep[e + 1], p2 = ep[e + 2], p3 = ep[e + 3];
        half4v x0 = *(const half4v*)(h + (size_t)p0.s * HC + c);
        half4v x1 = *(const half4v*)(h + (size_t)p1.s * HC + c);
        half4v x2 = *(const half4v*)(h + (size_t)p2.s * HC + c);
        half4v x3 = *(const half4v*)(h + (size_t)p3.s * HC + c);
        a0 += p0.w * (float)x0[0] + p1.w * (float)x1[0] + p2.w * (float)x2[0] + p3.w * (float)x3[0];
        a1 += p0.w * (float)x0[1] + p1.w * (float)x1[1] + p2.w * (float)x2[1] + p3.w * (float)x3[1];
        a2 += p0.w * (float)x0[2] + p1.w * (float)x1[2] + p2.w * (float)x2[2] + p3.w * (float)x3[2];
        a3 += p0.w * (float)x0[3] + p1.w * (float)x1[3] + p2.w * (float)x2[3] + p3.w * (float)x3[3];
      }
      for (; e < en; ++e) {
        EdgeP p0 = ep[e];
        half4v x0 = *(const half4v*)(h + (size_t)p0.s * HC + c);
        a0 += p0.w * (float)x0[0];
        a1 += p0.w * (float)x0[1];
        a2 += p0.w * (float)x0[2];
        a3 += p0.w * (float)x0[3];
      }
      half4v h0v = *(const half4v*)(h0 + base);
      half4v mo = { (_Float16)(0.9f * a0 + 0.1f * (float)h0v[0]),
                    (_Float16)(0.9f * a1 + 0.1f * (float)h0v[1]),
                    (_Float16)(0.9f * a2 + 0.1f * (float)h0v[2]),
                    (_Float16)(0.9f * a3 + 0.1f * (float)h0v[3]) };
      *(half4v*)&M[lrow][c] = mo;
    } else {
      *(half4v*)&M[lrow][c] = half4v{ (_Float16)0, (_Float16)0, (_Float16)0, (_Float16)0 };
    }
  }
  __syncthreads();

  // ---- phase 2: dense from M (K = HC = 256, fully unrolled)
  int r = lane & 15, g = lane >> 4;
  int c0 = wave * 64;
  floatx4 acc[4][4] = {};
#pragma unroll
  for (int ks = 0; ks < HC; ks += 32) {
    half8 a[4], b[4];
#pragma unroll
    for (int rt = 0; rt < 4; ++rt)
      a[rt] = *(const half8*)&M[rt * 16 + r][ks + g * 8];
#pragma unroll
    for (int ct = 0; ct < 4; ++ct)
      b[ct] = *(const half8*)(WT + (size_t)(c0 + ct * 16 + r) * HC + ks + g * 8);
#pragma unroll
    for (int rt = 0; rt < 4; ++rt)
#pragma unroll
      for (int ct = 0; ct < 4; ++ct)
        acc[rt][ct] = __builtin_amdgcn_mfma_f32_16x16x32_f16(a[rt], b[ct], acc[rt][ct], 0, 0, 0);
  }
  __syncthreads();   // drain all A-frag LDS reads before epilogue overwrites M

  // ---- epilogue
#pragma unroll
  for (int rt = 0; rt < 4; ++rt) {
#pragma unroll
    for (int q = 0; q < 4; ++q) {
      int lrow = rt * 16 + g * 4 + q;
#pragma unroll
      for (int ct = 0; ct < 4; ++ct) {
        int col = c0 + ct * 16 + r;
        float v = ob * (float)M[lrow][col] + beta * acc[rt][ct][q];
        if constexpr (!LAST) {
          v = fmaxf(v, 0.0f);
          M[lrow][col] = (_Float16)v;     // thread-own (row,col): safe RAW
        } else {
          int row = row0 + lrow;
          if (row < NNODES) outf[(size_t)row * HC + col] = v;
        }
      }
    }
  }
  if constexpr (!LAST) {
    __syncthreads();
    int lrow = t >> 2, cc = (t & 3) * 64;
    int grow = row0 + lrow;
    if (grow < NNODES) {
      size_t base = (size_t)grow * HC + cc;
#pragma unroll
      for (int i = 0; i < 8; ++i)
        *(half8*)(hn + base + i * 8) = *(const half8*)&M[lrow][cc + i * 8];
    }
  }
}

// ---------------- host ----------------

extern "C" void kernel_launch(void* const* d_in, const int* in_sizes, int n_in,
                              void* d_out, int out_size, void* d_ws, size_t ws_size,
                              hipStream_t stream) {
  const float* x = (const float*)d_in[0];
  const void* ei = d_in[1];                    // int32 or int64 — detected on device
  const float* wemb = (const float*)d_in[2];   // [512][256]
  const float* bemb = (const float*)d_in[3];
  const float* wc = (const float*)d_in[4];     // [8][256][256]
  (void)in_sizes; (void)n_in; (void)out_size; (void)ws_size;

  char* ws = (char*)d_ws;
  size_t o = 0;
  auto alloc = [&](size_t bytes) -> char* {
    char* p = ws + o;
    o = (o + bytes + 511) & ~(size_t)511;
    return p;
  };
  // total workspace ~118.2 MB (proven budget)
  _Float16* hh      = (_Float16*)alloc((size_t)NNODES * HC * 2);  // 51.2 MB
  _Float16* h0h     = (_Float16*)alloc((size_t)NNODES * HC * 2);  // 51.2 MB
  EdgeP*    ep      = (EdgeP*)alloc((size_t)NEDGES * 8);          // 12.8 MB
  _Float16* wembT   = (_Float16*)alloc((size_t)INC * HC * 2);     // 0.26 MB
  _Float16* wcT     = (_Float16*)alloc((size_t)NLAYERS * HC * HC * 2);  // 1.05 MB
  int*      counts  = (int*)alloc((size_t)NNODES * 4);
  int*      cursor  = (int*)alloc((size_t)NNODES * 4);
  int*      rowptr  = (int*)alloc((size_t)(NNODES + 1) * 4);
  float*    dinv    = (float*)alloc((size_t)NNODES * 4);
  int*      partials= (int*)alloc(2048);
  int*      mode    = (int*)alloc(256);
  _Float16* hd      = (_Float16*)d_out;        // f16 h ping-pong buffer in d_out (51.2 of 102.4 MB)

  const int NB = (NNODES + 255) / 256;       // 391
  const int GEMM_GRID = (NNODES + 63) / 64;  // 1563

  k_detect<<<1, 64, 0, stream>>>((const unsigned int*)ei, mode);
  k_zero2<<<NB, 256, 0, stream>>>(counts, cursor, NNODES);
  k_tr_wemb<<<(INC * HC) / 256, 256, 0, stream>>>(wemb, wembT);
  k_tr_wc<<<(NLAYERS * HC * HC) / 256, 256, 0, stream>>>(wc, wcT);
  k_count<<<(NEDGES + 255) / 256, 256, 0, stream>>>(ei, mode, counts);
  k_dinv<<<NB, 256, 0, stream>>>(counts, dinv);
  k_scan1<<<NB, 256, 0, stream>>>(counts, rowptr, partials);
  k_scan2<<<1, 512, 0, stream>>>(partials, rowptr, NB);
  k_scan3<<<NB, 256, 0, stream>>>(rowptr, partials);
  k_fill<<<(NEDGES + 255) / 256, 256, 0, stream>>>(ei, mode, rowptr, cursor, dinv, ep);

  // h1 = relu(x @ Wemb + b) -> hd (d_out region) and h0h
  k_dense<INC, false, true, false, true, true><<<GEMM_GRID, 256, 0, stream>>>(
      x, wembT, bemb, (const void*)nullptr, 0.0f, 1.0f, hd, h0h, (float*)nullptr);

  // ping-pong: hd -> hh -> hd -> ... ; layer 8 (last) reads hh, writes f32 d_out
  _Float16* cur = hd;
  _Float16* nxt = hh;
  for (int l = 0; l < NLAYERS; ++l) {
    float beta = (float)log(0.5 / (double)(l + 1) + 1.0);
    float ob = 1.0f - beta;
    const _Float16* W = wcT + (size_t)l * HC * HC;
    if (l < NLAYERS - 1) {
      k_layer<false><<<GEMM_GRID, 256, 0, stream>>>(cur, h0h, rowptr, ep, dinv, W,
                                                    ob, beta, nxt, (float*)nullptr);
      _Float16* tmp = cur; cur = nxt; nxt = tmp;
    } else {
      // parity: after embed(cur=hd) + 7 swaps, cur == hh (ws) — safe to write f32 into d_out
      k_layer<true><<<GEMM_GRID, 256, 0, stream>>>(cur, h0h, rowptr, ep, dinv, W,
                                                   ob, beta, (_Float16*)nullptr, (float*)d_out);
    }
  }
}

// Round 8
// 1932.171 us; speedup vs baseline: 1.2051x; 1.2051x over previous
//
#include <hip/hip_runtime.h>
#include <cmath>

#define NNODES 100000
#define NEDGES 1600000
#define INC 512
#define HC 256
#define NLAYERS 8

typedef _Float16 half8 __attribute__((ext_vector_type(8)));
typedef _Float16 half4v __attribute__((ext_vector_type(4)));
typedef float floatx4 __attribute__((ext_vector_type(4)));

struct __attribute__((aligned(8))) EdgeP { int s; float w; };

// ---- edge dtype detection: int64 little-endian with values < 2^31 => odd 32-bit words all zero.
__global__ void k_detect(const unsigned int* __restrict__ eb, int* __restrict__ mode) {
  int lane = threadIdx.x;  // 64 threads
  unsigned v = eb[2 * lane + 1];
  unsigned long long nz = __ballot(v != 0u);
  if (lane == 0) *mode = (nz == 0ull) ? 1 : 0;
}

__device__ __forceinline__ int edge_at(const void* eb, int m, int i) {
  return m ? (int)((const long long*)eb)[i] : ((const int*)eb)[i];
}

// ---------------- CSR build (unchanged, green since R3) ----------------

__global__ __launch_bounds__(256) void k_zero2(int* __restrict__ a, int* __restrict__ b, int n) {
  int i = blockIdx.x * 256 + threadIdx.x;
  if (i < n) { a[i] = 0; b[i] = 0; }
}

__global__ __launch_bounds__(256) void k_count(const void* __restrict__ eb, const int* __restrict__ mode,
                                               int* __restrict__ counts) {
  int e = blockIdx.x * 256 + threadIdx.x;
  if (e >= NEDGES) return;
  int m = *mode;
  atomicAdd(&counts[edge_at(eb, m, NEDGES + e)], 1);
}

__global__ __launch_bounds__(256) void k_dinv(const int* __restrict__ counts, float* __restrict__ dinv) {
  int i = blockIdx.x * 256 + threadIdx.x;
  if (i < NNODES) dinv[i] = 1.0f / sqrtf((float)counts[i] + 1.0f);  // +1 self loop
}

__global__ __launch_bounds__(256) void k_scan1(const int* __restrict__ counts, int* __restrict__ rowptr,
                                               int* __restrict__ partials) {
  __shared__ int sm[256];
  int i = blockIdx.x * 256 + threadIdx.x;
  int v = (i < NNODES) ? counts[i] : 0;
  sm[threadIdx.x] = v;
  __syncthreads();
  for (int off = 1; off < 256; off <<= 1) {
    int u = (threadIdx.x >= off) ? sm[threadIdx.x - off] : 0;
    __syncthreads();
    sm[threadIdx.x] += u;
    __syncthreads();
  }
  if (i < NNODES) rowptr[i] = sm[threadIdx.x] - v;
  if (threadIdx.x == 255) partials[blockIdx.x] = sm[255];
}

__global__ __launch_bounds__(512) void k_scan2(int* __restrict__ partials, int* __restrict__ rowptr, int nb) {
  __shared__ int sm[512];
  int t = threadIdx.x;
  int v = (t < nb) ? partials[t] : 0;
  sm[t] = v;
  __syncthreads();
  for (int off = 1; off < 512; off <<= 1) {
    int u = (t >= off) ? sm[t - off] : 0;
    __syncthreads();
    sm[t] += u;
    __syncthreads();
  }
  if (t < nb) partials[t] = sm[t] - v;
  if (t == 0) rowptr[NNODES] = NEDGES;
}

__global__ __launch_bounds__(256) void k_scan3(int* __restrict__ rowptr, const int* __restrict__ partials) {
  int i = blockIdx.x * 256 + threadIdx.x;
  if (i < NNODES) rowptr[i] += partials[blockIdx.x];
}

__global__ __launch_bounds__(256) void k_fill(const void* __restrict__ eb, const int* __restrict__ mode,
                                              const int* __restrict__ rowptr,
                                              int* __restrict__ cursor, const float* __restrict__ dinv,
                                              EdgeP* __restrict__ ep) {
  int e = blockIdx.x * 256 + threadIdx.x;
  if (e >= NEDGES) return;
  int m = *mode;
  int r = edge_at(eb, m, e), c = edge_at(eb, m, NEDGES + e);
  int p = rowptr[c] + atomicAdd(&cursor[c], 1);
  EdgeP pr; pr.s = r; pr.w = dinv[r] * dinv[c];
  ep[p] = pr;
}

// ---------------- weight transposes to f16 ----------------
__global__ __launch_bounds__(256) void k_tr_wemb(const float* __restrict__ W, _Float16* __restrict__ WT) {
  int idx = blockIdx.x * 256 + threadIdx.x;        // 131072 = c*512 + k
  int k = idx & 511, c = idx >> 9;
  WT[idx] = (_Float16)W[k * 256 + c];
}
__global__ __launch_bounds__(256) void k_tr_wc(const float* __restrict__ W, _Float16* __restrict__ WT) {
  int idx = blockIdx.x * 256 + threadIdx.x;        // 524288 = l*65536 + n*256 + k
  int k = idx & 255, n = (idx >> 8) & 255, l = idx >> 16;
  WT[idx] = (_Float16)W[(l * 256 + k) * 256 + n];
}

// ---------------- embed (unchanged, green): h0 = relu(x @ Wemb + b) ----------------

template <int K, bool AF16, bool BIAS, bool ID, bool RELU, bool F16OUT>
__global__ __launch_bounds__(256) void k_dense(const void* A, const _Float16* __restrict__ WT,
                                               const float* __restrict__ bias,
                                               const void* mfid,
                                               float ob, float beta,
                                               _Float16* __restrict__ outh, _Float16* __restrict__ outh2,
                                               float* outf) {
  int t = threadIdx.x;
  int wave = t >> 6, lane = t & 63;
  int r = lane & 15, g = lane >> 4;
  int row0 = blockIdx.x * 64;
  int c0 = wave * 64;
  int ar[4];
#pragma unroll
  for (int rt = 0; rt < 4; ++rt) {
    int rr = row0 + rt * 16 + r;
    ar[rt] = (rr < NNODES) ? rr : (NNODES - 1);
  }

  auto loadA = [&](half8 (&a)[4], int ks) {
#pragma unroll
    for (int rt = 0; rt < 4; ++rt) {
      if constexpr (AF16) {
        a[rt] = *(const half8*)((const _Float16*)A + (size_t)ar[rt] * K + ks + g * 8);
      } else {
        const float* ap = (const float*)A + (size_t)ar[rt] * K + ks + g * 8;
        float4 p0 = *(const float4*)ap;
        float4 p1 = *(const float4*)(ap + 4);
        a[rt] = half8{ (_Float16)p0.x, (_Float16)p0.y, (_Float16)p0.z, (_Float16)p0.w,
                       (_Float16)p1.x, (_Float16)p1.y, (_Float16)p1.z, (_Float16)p1.w };
      }
    }
  };
  auto loadB = [&](half8 (&b)[4], int ks) {
#pragma unroll
    for (int ct = 0; ct < 4; ++ct)
      b[ct] = *(const half8*)(WT + (size_t)(c0 + ct * 16 + r) * K + ks + g * 8);
  };

  floatx4 acc[4][4] = {};
  half8 aP[4], bP[4], aQ[4], bQ[4];
  loadA(aP, 0); loadB(bP, 0);
#pragma unroll
  for (int ks = 0; ks < K; ks += 64) {
    loadA(aQ, ks + 32); loadB(bQ, ks + 32);
#pragma unroll
    for (int rt = 0; rt < 4; ++rt)
#pragma unroll
      for (int ct = 0; ct < 4; ++ct)
        acc[rt][ct] = __builtin_amdgcn_mfma_f32_16x16x32_f16(aP[rt], bP[ct], acc[rt][ct], 0, 0, 0);
    if (ks + 64 < K) { loadA(aP, ks + 64); loadB(bP, ks + 64); }
#pragma unroll
    for (int rt = 0; rt < 4; ++rt)
#pragma unroll
      for (int ct = 0; ct < 4; ++ct)
        acc[rt][ct] = __builtin_amdgcn_mfma_f32_16x16x32_f16(aQ[rt], bQ[ct], acc[rt][ct], 0, 0, 0);
  }

  auto idval = [&](size_t off) -> float {
    if constexpr (AF16) return (float)((const _Float16*)mfid)[off];
    else return ((const float*)mfid)[off];
  };

  if constexpr (!F16OUT) {
    __syncthreads();
#pragma unroll
    for (int rt = 0; rt < 4; ++rt) {
#pragma unroll
      for (int q = 0; q < 4; ++q) {
        int row = row0 + rt * 16 + g * 4 + q;
        if (row >= NNODES) continue;
#pragma unroll
        for (int ct = 0; ct < 4; ++ct) {
          int col = c0 + ct * 16 + r;
          size_t off = (size_t)row * HC + col;
          float v = acc[rt][ct][q];
          if constexpr (ID) v = ob * idval(off) + beta * v;
          if constexpr (BIAS) v += bias[col];
          if constexpr (RELU) v = fmaxf(v, 0.0f);
          outf[off] = v;
        }
      }
    }
  } else {
    __shared__ _Float16 Cl[64][264];   // +8 f16 pad
#pragma unroll
    for (int rt = 0; rt < 4; ++rt) {
#pragma unroll
      for (int q = 0; q < 4; ++q) {
        int lrow = rt * 16 + g * 4 + q;
        int row = row0 + lrow;
        int crow = (row < NNODES) ? row : (NNODES - 1);
#pragma unroll
        for (int ct = 0; ct < 4; ++ct) {
          int col = c0 + ct * 16 + r;
          float v = acc[rt][ct][q];
          if constexpr (ID) v = ob * idval((size_t)crow * HC + col) + beta * v;
          if constexpr (BIAS) v += bias[col];
          if constexpr (RELU) v = fmaxf(v, 0.0f);
          Cl[lrow][col] = (_Float16)v;
        }
      }
    }
    __syncthreads();
    int lrow = t >> 2, cc = (t & 3) * 64;
    int grow = row0 + lrow;
    if (grow < NNODES) {
      size_t base = (size_t)grow * HC + cc;
#pragma unroll
      for (int i = 0; i < 8; ++i) {
        half8 v = *(const half8*)&Cl[lrow][cc + i * 8];
        *(half8*)(outh + base + i * 8) = v;
        if (outh2) *(half8*)(outh2 + base + i * 8) = v;
      }
    }
  }
}

// ---------------- fused layer (32-node tile): hn = relu( ob*m + beta*(m @ W) ) ----------------
// m = 0.9*(D^-1/2 A_hat D^-1/2 h) + 0.1*h0, staged in LDS M[32][264] f16 (16.9 KB ->
// 8 blocks/CU, 32 waves/CU: restores split-spmm gather concurrency; R7's 64-row tile
// capped at ~2 blocks/CU). Phase 1: wave gathers 8 nodes, edge loop unroll 8 (16
// independent loads in flight). Phase 2: MFMA dense from M (row stride 132 words ->
// 2-way banks = free). Epilogue identical to green R7: barrier, thread-own in-place
// M overwrite, barrier, coalesced half8 store. LAST: f32 direct store.

template <bool LAST>
__global__ __launch_bounds__(256) void k_layer(const _Float16* __restrict__ h,
                                               const _Float16* __restrict__ h0,
                                               const int* __restrict__ rowptr,
                                               const EdgeP* __restrict__ ep,
                                               const float* __restrict__ dinv,
                                               const _Float16* __restrict__ WT,
                                               float ob, float beta,
                                               _Float16* __restrict__ hn, float* __restrict__ outf) {
  __shared__ _Float16 M[32][264];
  int t = threadIdx.x;
  int wave = t >> 6, lane = t & 63;
  int row0 = blockIdx.x * 32;
  int c = lane * 4;

  // ---- phase 1: spmm + residual into M (8 nodes per wave)
  for (int i = 0; i < 8; ++i) {
    int lrow = wave * 8 + i;
    int node = row0 + lrow;
    if (node < NNODES) {
      size_t base = (size_t)node * HC + c;
      float di = dinv[node];
      float wsw = di * di;
      half4v hv = *(const half4v*)(h + base);
      float a0 = wsw * (float)hv[0], a1 = wsw * (float)hv[1];
      float a2 = wsw * (float)hv[2], a3 = wsw * (float)hv[3];
      int e = rowptr[node], en = rowptr[node + 1];
      for (; e + 7 < en; e += 8) {
        EdgeP p0 = ep[e],     p1 = ep[e + 1], p2 = ep[e + 2], p3 = ep[e + 3];
        EdgeP p4 = ep[e + 4], p5 = ep[e + 5], p6 = ep[e + 6], p7 = ep[e + 7];
        half4v x0 = *(const half4v*)(h + (size_t)p0.s * HC + c);
        half4v x1 = *(const half4v*)(h + (size_t)p1.s * HC + c);
        half4v x2 = *(const half4v*)(h + (size_t)p2.s * HC + c);
        half4v x3 = *(const half4v*)(h + (size_t)p3.s * HC + c);
        half4v x4 = *(const half4v*)(h + (size_t)p4.s * HC + c);
        half4v x5 = *(const half4v*)(h + (size_t)p5.s * HC + c);
        half4v x6 = *(const half4v*)(h + (size_t)p6.s * HC + c);
        half4v x7 = *(const half4v*)(h + (size_t)p7.s * HC + c);
        a0 += p0.w * (float)x0[0] + p1.w * (float)x1[0] + p2.w * (float)x2[0] + p3.w * (float)x3[0]
            + p4.w * (float)x4[0] + p5.w * (float)x5[0] + p6.w * (float)x6[0] + p7.w * (float)x7[0];
        a1 += p0.w * (float)x0[1] + p1.w * (float)x1[1] + p2.w * (float)x2[1] + p3.w * (float)x3[1]
            + p4.w * (float)x4[1] + p5.w * (float)x5[1] + p6.w * (float)x6[1] + p7.w * (float)x7[1];
        a2 += p0.w * (float)x0[2] + p1.w * (float)x1[2] + p2.w * (float)x2[2] + p3.w * (float)x3[2]
            + p4.w * (float)x4[2] + p5.w * (float)x5[2] + p6.w * (float)x6[2] + p7.w * (float)x7[2];
        a3 += p0.w * (float)x0[3] + p1.w * (float)x1[3] + p2.w * (float)x2[3] + p3.w * (float)x3[3]
            + p4.w * (float)x4[3] + p5.w * (float)x5[3] + p6.w * (float)x6[3] + p7.w * (float)x7[3];
      }
      for (; e + 3 < en; e += 4) {
        EdgeP p0 = ep[e], p1 = ep[e + 1], p2 = ep[e + 2], p3 = ep[e + 3];
        half4v x0 = *(const half4v*)(h + (size_t)p0.s * HC + c);
        half4v x1 = *(const half4v*)(h + (size_t)p1.s * HC + c);
        half4v x2 = *(const half4v*)(h + (size_t)p2.s * HC + c);
        half4v x3 = *(const half4v*)(h + (size_t)p3.s * HC + c);
        a0 += p0.w * (float)x0[0] + p1.w * (float)x1[0] + p2.w * (float)x2[0] + p3.w * (float)x3[0];
        a1 += p0.w * (float)x0[1] + p1.w * (float)x1[1] + p2.w * (float)x2[1] + p3.w * (float)x3[1];
        a2 += p0.w * (float)x0[2] + p1.w * (float)x1[2] + p2.w * (float)x2[2] + p3.w * (float)x3[2];
        a3 += p0.w * (float)x0[3] + p1.w * (float)x1[3] + p2.w * (float)x2[3] + p3.w * (float)x3[3];
      }
      for (; e < en; ++e) {
        EdgeP p0 = ep[e];
        half4v x0 = *(const half4v*)(h + (size_t)p0.s * HC + c);
        a0 += p0.w * (float)x0[0];
        a1 += p0.w * (float)x0[1];
        a2 += p0.w * (float)x0[2];
        a3 += p0.w * (float)x0[3];
      }
      half4v h0v = *(const half4v*)(h0 + base);
      half4v mo = { (_Float16)(0.9f * a0 + 0.1f * (float)h0v[0]),
                    (_Float16)(0.9f * a1 + 0.1f * (float)h0v[1]),
                    (_Float16)(0.9f * a2 + 0.1f * (float)h0v[2]),
                    (_Float16)(0.9f * a3 + 0.1f * (float)h0v[3]) };
      *(half4v*)&M[lrow][c] = mo;
    } else {
      *(half4v*)&M[lrow][c] = half4v{ (_Float16)0, (_Float16)0, (_Float16)0, (_Float16)0 };
    }
  }
  __syncthreads();

  // ---- phase 2: dense from M (K = HC = 256, fully unrolled)
  int r = lane & 15, g = lane >> 4;
  int c0 = wave * 64;
  floatx4 acc[2][4] = {};
#pragma unroll
  for (int ks = 0; ks < HC; ks += 32) {
    half8 a[2], b[4];
    a[0] = *(const half8*)&M[r][ks + g * 8];
    a[1] = *(const half8*)&M[16 + r][ks + g * 8];
#pragma unroll
    for (int ct = 0; ct < 4; ++ct)
      b[ct] = *(const half8*)(WT + (size_t)(c0 + ct * 16 + r) * HC + ks + g * 8);
#pragma unroll
    for (int rt = 0; rt < 2; ++rt)
#pragma unroll
      for (int ct = 0; ct < 4; ++ct)
        acc[rt][ct] = __builtin_amdgcn_mfma_f32_16x16x32_f16(a[rt], b[ct], acc[rt][ct], 0, 0, 0);
  }
  __syncthreads();   // drain all A-frag LDS reads before epilogue overwrites M

  // ---- epilogue
#pragma unroll
  for (int rt = 0; rt < 2; ++rt) {
#pragma unroll
    for (int q = 0; q < 4; ++q) {
      int lrow = rt * 16 + g * 4 + q;
#pragma unroll
      for (int ct = 0; ct < 4; ++ct) {
        int col = c0 + ct * 16 + r;
        float v = ob * (float)M[lrow][col] + beta * acc[rt][ct][q];
        if constexpr (!LAST) {
          v = fmaxf(v, 0.0f);
          M[lrow][col] = (_Float16)v;     // thread-own (row,col): safe RAW
        } else {
          int row = row0 + lrow;
          if (row < NNODES) outf[(size_t)row * HC + col] = v;
        }
      }
    }
  }
  if constexpr (!LAST) {
    __syncthreads();
    int lrow = t >> 3, cc = (t & 7) * 32;   // 8 threads/row, 32 f16 each
    int grow = row0 + lrow;
    if (grow < NNODES) {
      size_t base = (size_t)grow * HC + cc;
#pragma unroll
      for (int i = 0; i < 4; ++i)
        *(half8*)(hn + base + i * 8) = *(const half8*)&M[lrow][cc + i * 8];
    }
  }
}

// ---------------- host ----------------

extern "C" void kernel_launch(void* const* d_in, const int* in_sizes, int n_in,
                              void* d_out, int out_size, void* d_ws, size_t ws_size,
                              hipStream_t stream) {
  const float* x = (const float*)d_in[0];
  const void* ei = d_in[1];                    // int32 or int64 — detected on device
  const float* wemb = (const float*)d_in[2];   // [512][256]
  const float* bemb = (const float*)d_in[3];
  const float* wc = (const float*)d_in[4];     // [8][256][256]
  (void)in_sizes; (void)n_in; (void)out_size; (void)ws_size;

  char* ws = (char*)d_ws;
  size_t o = 0;
  auto alloc = [&](size_t bytes) -> char* {
    char* p = ws + o;
    o = (o + bytes + 511) & ~(size_t)511;
    return p;
  };
  // total workspace ~118.2 MB (proven budget)
  _Float16* hh      = (_Float16*)alloc((size_t)NNODES * HC * 2);  // 51.2 MB
  _Float16* h0h     = (_Float16*)alloc((size_t)NNODES * HC * 2);  // 51.2 MB
  EdgeP*    ep      = (EdgeP*)alloc((size_t)NEDGES * 8);          // 12.8 MB
  _Float16* wembT   = (_Float16*)alloc((size_t)INC * HC * 2);     // 0.26 MB
  _Float16* wcT     = (_Float16*)alloc((size_t)NLAYERS * HC * HC * 2);  // 1.05 MB
  int*      counts  = (int*)alloc((size_t)NNODES * 4);
  int*      cursor  = (int*)alloc((size_t)NNODES * 4);
  int*      rowptr  = (int*)alloc((size_t)(NNODES + 1) * 4);
  float*    dinv    = (float*)alloc((size_t)NNODES * 4);
  int*      partials= (int*)alloc(2048);
  int*      mode    = (int*)alloc(256);
  _Float16* hd      = (_Float16*)d_out;        // f16 h ping-pong buffer in d_out

  const int NB = (NNODES + 255) / 256;        // 391
  const int GEMM_GRID = (NNODES + 63) / 64;   // 1563
  const int LAYER_GRID = (NNODES + 31) / 32;  // 3125

  k_detect<<<1, 64, 0, stream>>>((const unsigned int*)ei, mode);
  k_zero2<<<NB, 256, 0, stream>>>(counts, cursor, NNODES);
  k_tr_wemb<<<(INC * HC) / 256, 256, 0, stream>>>(wemb, wembT);
  k_tr_wc<<<(NLAYERS * HC * HC) / 256, 256, 0, stream>>>(wc, wcT);
  k_count<<<(NEDGES + 255) / 256, 256, 0, stream>>>(ei, mode, counts);
  k_dinv<<<NB, 256, 0, stream>>>(counts, dinv);
  k_scan1<<<NB, 256, 0, stream>>>(counts, rowptr, partials);
  k_scan2<<<1, 512, 0, stream>>>(partials, rowptr, NB);
  k_scan3<<<NB, 256, 0, stream>>>(rowptr, partials);
  k_fill<<<(NEDGES + 255) / 256, 256, 0, stream>>>(ei, mode, rowptr, cursor, dinv, ep);

  // h1 = relu(x @ Wemb + b) -> hd (d_out region) and h0h
  k_dense<INC, false, true, false, true, true><<<GEMM_GRID, 256, 0, stream>>>(
      x, wembT, bemb, (const void*)nullptr, 0.0f, 1.0f, hd, h0h, (float*)nullptr);

  // ping-pong: hd -> hh -> hd -> ... ; layer 8 (last) reads hh, writes f32 d_out
  _Float16* cur = hd;
  _Float16* nxt = hh;
  for (int l = 0; l < NLAYERS; ++l) {
    float beta = (float)log(0.5 / (double)(l + 1) + 1.0);
    float ob = 1.0f - beta;
    const _Float16* W = wcT + (size_t)l * HC * HC;
    if (l < NLAYERS - 1) {
      k_layer<false><<<LAYER_GRID, 256, 0, stream>>>(cur, h0h, rowptr, ep, dinv, W,
                                                     ob, beta, nxt, (float*)nullptr);
      _Float16* tmp = cur; cur = nxt; nxt = tmp;
    } else {
      // parity: after embed(cur=hd) + 7 swaps, cur == hh (ws) — safe to write f32 into d_out
      k_layer<true><<<LAYER_GRID, 256, 0, stream>>>(cur, h0h, rowptr, ep, dinv, W,
                                                    ob, beta, (_Float16*)nullptr, (float*)d_out);
    }
  }
}